// Round 10
// baseline (1675.985 us; speedup 1.0000x reference)
//
#include <hip/hip_runtime.h>
#include <hip/hip_fp16.h>

#define NN 50000
#define TT 12
#define EE 800000
#define IN_C 32
#define HID 64
#define OUT_C 32
#define BSZ 16                        // nodes per fine bucket
#define NBF (NN / BSZ)                // 3125 (exact)
#define CAPF 400                      // slots per (t,bucket); mean 256, +9 sigma
#define EPB 8192                      // edges per bin block
#define ABLK ((EE + EPB - 1) / EPB)   // 98
#define XPAIRS ((size_t)TT * NN * 16) // half2 elements in x

// ---------------- precompute folded gate matrices ----------------
// Mz = Wz @ Lz_w[:64] (32x64), Bz = bz @ Lz_w[:64] + Lz_b (64); same for h.
__global__ __launch_bounds__(64) void prep_kernel(
    const float* __restrict__ Wz, const float* __restrict__ bz,
    const float* __restrict__ Lzw, const float* __restrict__ Lzb,
    const float* __restrict__ Wh, const float* __restrict__ bh,
    const float* __restrict__ Lhw, const float* __restrict__ Lhb,
    float* __restrict__ Mz, float* __restrict__ Bz,
    float* __restrict__ Mh, float* __restrict__ Bh) {
  const int j = threadIdx.x;
  const int i = blockIdx.x;
  const int h = blockIdx.y;
  const float* W  = h ? Wh  : Wz;
  const float* b  = h ? bh  : bz;
  const float* L  = h ? Lhw : Lzw;
  const float* Lb = h ? Lhb : Lzb;
  float* M = h ? Mh : Mz;
  float* B = h ? Bh : Bz;
  if (i < IN_C) {
    float v = 0.f;
    for (int k = 0; k < HID; ++k) v += W[i * HID + k] * L[k * HID + j];
    M[i * HID + j] = v;
  } else {
    float v = Lb[j];
    for (int k = 0; k < HID; ++k) v += b[k] * L[k * HID + j];
    B[j] = v;
  }
}

// x [T,N,32] fp32 -> fp16 pairs
__global__ __launch_bounds__(256) void xconv_kernel(const float* __restrict__ x,
                                                    __half2* __restrict__ xh) {
  size_t i = (size_t)blockIdx.x * 256 + threadIdx.x;
  if (i < XPAIRS) {
    float2 f = ((const float2*)x)[i];
    xh[i] = __floats2half2_rn(f.x, f.y);
  }
}

// Pass A: fine-bucket multisplit. Each block: LDS hist over NBF buckets,
// one global atomic per touched bucket grabs a contiguous range, then
// places entries {src16 | (dst&15)<<16 | w16<<32} bucket-grouped.
__global__ __launch_bounds__(256) void bin_kernel(const int* __restrict__ ei,
                                                  const float* __restrict__ ew,
                                                  int* __restrict__ cursorA,
                                                  unsigned long long* __restrict__ binA,
                                                  int tbase) {
  __shared__ int hist[NBF];
  __shared__ int rnk[NBF];
  int tl = blockIdx.y;
  const int* src = ei + (size_t)(tbase + tl) * 2 * EE;
  const int* dst = src + EE;
  const float* w = ew + (size_t)(tbase + tl) * EE;
  int* cursor = cursorA + (size_t)tl * NBF;
  unsigned long long* bin = binA + (size_t)tl * NBF * CAPF;
  int t = threadIdx.x;
  for (int i = t; i < NBF; i += 256) { hist[i] = 0; rnk[i] = 0; }
  __syncthreads();
  int e0 = blockIdx.x * EPB;
#pragma unroll
  for (int i = 0; i < EPB / 256; ++i) {
    int e = e0 + i * 256 + t;
    if (e < EE) atomicAdd(&hist[dst[e] >> 4], 1);
  }
  __syncthreads();
  for (int b = t; b < NBF; b += 256)
    hist[b] = atomicAdd(&cursor[b], hist[b]);  // hist becomes this block's base
  __syncthreads();
#pragma unroll
  for (int i = 0; i < EPB / 256; ++i) {
    int e = e0 + i * 256 + t;
    if (e < EE) {
      int d = dst[e], s = src[e];
      int b = d >> 4;
      unsigned short hw = __half_as_ushort(__float2half_rn(w[e]));
      int pos = hist[b] + atomicAdd(&rnk[b], 1);
      if (pos < CAPF)
        bin[(size_t)b * CAPF + pos] =
            (unsigned long long)((unsigned)s | ((unsigned)(d & 15) << 16)) |
            ((unsigned long long)hw << 32);
    }
  }
}

// per (bucket,t): deg = 1 + sum w over bucket entries (LDS), dinv = rsqrt(deg)
__global__ __launch_bounds__(256) void deg_kernel(const int* __restrict__ cursorA,
                                                  const unsigned long long* __restrict__ binA,
                                                  float* __restrict__ dinvA) {
  __shared__ float wsum[BSZ];
  int tl = blockIdx.y, b = blockIdx.x;
  int t = threadIdx.x;
  if (t < BSZ) wsum[t] = 0.f;
  __syncthreads();
  int cnt = min(cursorA[(size_t)tl * NBF + b], CAPF);
  const unsigned long long* bin = binA + ((size_t)tl * NBF + b) * CAPF;
  for (int i = t; i < cnt; i += 256) {
    unsigned long long u = bin[i];
    int dl = (int)((u >> 16) & 15u);
    float wv = __half2float(__ushort_as_half((unsigned short)(u >> 32)));
    atomicAdd(&wsum[dl], wv);
  }
  __syncthreads();
  if (t < BSZ) dinvA[(size_t)tl * NN + b * BSZ + t] = rsqrtf(1.0f + wsum[t]);
}

// Pass B: block (256 thr, 4 waves) per fine bucket of 16 nodes; t-loop inside
// (t-lockstep -> xh_t L2-resident). Per t: in-LDS counting sort by dst&15
// (dinv[src] folded into fp16 norm at place time), then NODE-PARALLEL gather:
// 16 lanes per node (4 nodes per wave concurrent) = 8 independent x-rows per
// wave VMEM instr. One shfl_xor(8) reduce. Register acc across all t.
__global__ __launch_bounds__(256) void gather_agg_kernel(
    const float* __restrict__ x, const __half2* __restrict__ xh,
    const float* __restrict__ dinvA, const int* __restrict__ cursorA,
    const unsigned long long* __restrict__ binA,
    const float* __restrict__ Mz, const float* __restrict__ Bz,
    const float* __restrict__ Mh, const float* __restrict__ Bh,
    float* __restrict__ acc, int tbase, int nt) {
  __shared__ float sMz[IN_C * HID], sMh[IN_C * HID], sBz[HID], sBh[HID];
  __shared__ unsigned sbuf[CAPF];   // sorted {src16 | fp16(w*dinv[s])<<16}
  __shared__ int noff[BSZ + 1];
  __shared__ int plc[BSZ];
  __shared__ float yt[4][4][IN_C];  // [wave][node-in-wave][channel]
  int t = threadIdx.x;
  for (int i = t; i < IN_C * HID; i += 256) { sMz[i] = Mz[i]; sMh[i] = Mh[i]; }
  if (t < HID) { sBz[t] = Bz[t]; sBh[t] = Bh[t]; }

  int bb = blockIdx.x;
  int nbase = bb * BSZ;
  int w = t >> 6;       // wave 0..3
  int lane = t & 63;
  int m = lane >> 4;    // node-in-wave 0..3
  int sl = lane & 15;
  int p = sl >> 3;      // edge parity 0/1
  int cl = sl & 7;      // channel quad 0..7
  int nl = (w << 2) | m;  // local node 0..15
  int n = nbase + nl;     // global node (NN % 16 == 0, no tail)
  float accr[4];
#pragma unroll
  for (int k = 0; k < 4; ++k) accr[k] = 0.f;

  for (int tl = 0; tl < nt; ++tl) {
    __syncthreads();  // previous iteration's sbuf/noff reads done
    if (t < BSZ + 1) noff[t] = 0;
    __syncthreads();
    int cnt = min(cursorA[(size_t)tl * NBF + bb], CAPF);
    const unsigned long long* bin = binA + ((size_t)tl * NBF + bb) * CAPF;
    // histogram by node-low-4
    for (int e = t; e < cnt; e += 256)
      atomicAdd(&noff[(int)((bin[e] >> 16) & 15u)], 1);
    __syncthreads();
    if (t == 0) {  // serial exclusive scan over 16 nodes
      int run = 0;
#pragma unroll
      for (int i = 0; i < BSZ; ++i) {
        int c = noff[i];
        noff[i] = run;
        plc[i] = run;
        run += c;
      }
      noff[BSZ] = run;
    }
    __syncthreads();
    const float* dinv = dinvA + (size_t)tl * NN;
    // place sorted, folding dinv[src] into the fp16 norm
    for (int e = t; e < cnt; e += 256) {
      unsigned long long u = bin[e];
      int s = (int)(u & 0xFFFFu);
      int dl = (int)((u >> 16) & 15u);
      float nm = __half2float(__ushort_as_half((unsigned short)(u >> 32))) * dinv[s];
      int pos = atomicAdd(&plc[dl], 1);
      sbuf[pos] = (unsigned)s |
                  ((unsigned)__half_as_ushort(__float2half_rn(nm)) << 16);
    }
    __syncthreads();
    // node-parallel gather: 16 lanes per node, 2 edges in flight per node
    const __half2* xht = xh + (size_t)(tbase + tl) * NN * 16;
    const float* xt = x + (size_t)(tbase + tl) * NN * IN_C;
    int e0 = noff[nl], e1 = noff[nl + 1];
    float4 v = {0.f, 0.f, 0.f, 0.f};
    for (int e = e0 + p; e < e1; e += 2) {
      unsigned u = sbuf[e];  // 16 lanes same addr: LDS broadcast
      float nm = __half2float(__ushort_as_half((unsigned short)(u >> 16)));
      uint2 xr = ((const uint2*)(xht + (size_t)(u & 0xFFFFu) * 16))[cl];
      float2 p0 = __half22float2(*(const __half2*)&xr.x);
      float2 p1 = __half22float2(*(const __half2*)&xr.y);
      v.x += nm * p0.x; v.y += nm * p0.y;
      v.z += nm * p1.x; v.w += nm * p1.y;
    }
    // combine the two edge-parity partials (lane ^ 8 keeps node & quad)
    v.x += __shfl_xor(v.x, 8);
    v.y += __shfl_xor(v.y, 8);
    v.z += __shfl_xor(v.z, 8);
    v.w += __shfl_xor(v.w, 8);
    float dv = dinv[n];
    if (p == 0) {  // 8 lanes x float4 = all 32 channels; fp32 self-loop
      float4 xs = ((const float4*)(xt + (size_t)n * IN_C))[cl];
      float4 o;
      o.x = dv * (v.x + dv * xs.x);
      o.y = dv * (v.y + dv * xs.y);
      o.z = dv * (v.z + dv * xs.z);
      o.w = dv * (v.w + dv * xs.w);
      *(float4*)&yt[w][m][cl * 4] = o;  // wave-private: in-order, no barrier
    }
    // gate: per wave, 4 nodes serial; all 64 lanes = 64 columns
#pragma unroll
    for (int k = 0; k < 4; ++k) {
      const float* yrow = yt[w][k];
      float za = sBz[lane], ha = sBh[lane];
#pragma unroll
      for (int c = 0; c < IN_C; ++c) {
        float yv = yrow[c];  // wave-broadcast
        za += yv * sMz[c * HID + lane];
        ha += yv * sMh[c * HID + lane];
      }
      float z = 1.0f / (1.0f + expf(-za));
      accr[k] += (1.0f - z) * tanhf(ha);
    }
  }
#pragma unroll
  for (int k = 0; k < 4; ++k) {
    int nk = nbase + (w << 2) + k;
    size_t ai = (size_t)nk * HID + lane;
    acc[ai] = (tbase == 0 ? 0.f : acc[ai]) + accr[k];
  }
}

// out[n][o] = (acc[n]/T) . W_out[:,o] + b_out[o]
__global__ __launch_bounds__(256) void out_kernel(const float* __restrict__ acc,
                                                  const float* __restrict__ W_out,
                                                  const float* __restrict__ b_out,
                                                  float* __restrict__ out) {
  __shared__ float sW[HID * OUT_C], sB[OUT_C];
  for (int i = threadIdx.x; i < HID * OUT_C; i += 256) sW[i] = W_out[i];
  if (threadIdx.x < OUT_C) sB[threadIdx.x] = b_out[threadIdx.x];
  __syncthreads();
  unsigned tid = blockIdx.x * 256u + threadIdx.x;
  unsigned n = tid >> 5;
  int o = tid & 31;
  if (n >= NN) return;
  const float* ar = acc + (size_t)n * HID;
  float v = 0.f;
#pragma unroll
  for (int k = 0; k < HID; ++k) v += ar[k] * sW[k * OUT_C + o];
  out[(size_t)n * OUT_C + o] = v * (1.0f / (float)TT) + sB[o];
}

static inline char* alignp(char* p, size_t a) {
  return (char*)(((size_t)p + a - 1) & ~(a - 1));
}

extern "C" void kernel_launch(void* const* d_in, const int* in_sizes, int n_in,
                              void* d_out, int out_size, void* d_ws, size_t ws_size,
                              hipStream_t stream) {
  const float* x     = (const float*)d_in[0];  // [T,N,32]
  const int*   ei    = (const int*)d_in[1];    // [T,2,E]
  const float* ew    = (const float*)d_in[2];  // [T,E]
  const float* Wz    = (const float*)d_in[3];
  const float* bz    = (const float*)d_in[4];
  // d_in[5..6] (Wr,br) dead: H==0 so R unused
  const float* Wh    = (const float*)d_in[7];
  const float* bh    = (const float*)d_in[8];
  const float* Lz_w  = (const float*)d_in[9];
  const float* Lz_b  = (const float*)d_in[10];
  // d_in[11..12] (Lr) dead
  const float* Lh_w  = (const float*)d_in[13];
  const float* Lh_b  = (const float*)d_in[14];
  const float* W_out = (const float*)d_in[15];
  const float* b_out = (const float*)d_in[16];
  float* out = (float*)d_out;

  // sizes (bytes)
  const size_t binB  = (size_t)NBF * CAPF * 8;  // 10.0 MB per t
  const size_t curB  = (size_t)NBF * 4;
  const size_t dinvB = (size_t)NN * 4;
  const size_t perT  = binB + curB + dinvB;     // ~10.2 MB
  const size_t xhB   = XPAIRS * 4;              // 38.4 MB
  const size_t fixedB = 4 * ((size_t)2 * IN_C * HID + 2 * HID)
                      + (size_t)NN * HID * 4 + xhB + 4096;  // ~51.3 MB

  int nt = 12;
  if (ws_size < fixedB + 12 * perT) {
    nt = (int)((ws_size - fixedB) / perT);
    if (nt < 1) nt = 1;
    if (nt > 12) nt = 12;
  }

  char* p = (char*)d_ws;
  unsigned long long* bin = (unsigned long long*)p;  // 8-aligned at base
  p += binB * nt;
  int* cursor = (int*)p;  p += curB * nt;
  float* dinv = (float*)p; p += dinvB * nt;
  float* Mz = (float*)p;
  float* Mh = Mz + IN_C * HID;
  float* Bz = Mh + IN_C * HID;
  float* Bh = Bz + HID;
  float* acc = Bh + HID;  // [N,64]
  p = alignp((char*)(acc + (size_t)NN * HID), 256);
  __half2* xh = (__half2*)p;

  prep_kernel<<<dim3(IN_C + 1, 2), 64, 0, stream>>>(Wz, bz, Lz_w, Lz_b, Wh, bh,
                                                    Lh_w, Lh_b, Mz, Bz, Mh, Bh);
  xconv_kernel<<<(unsigned)((XPAIRS + 255) / 256), 256, 0, stream>>>(x, xh);

  for (int tb = 0; tb < TT; tb += nt) {
    int c = (TT - tb < nt) ? (TT - tb) : nt;
    hipMemsetAsync(cursor, 0, curB * c, stream);
    bin_kernel<<<dim3(ABLK, c), 256, 0, stream>>>(ei, ew, cursor, bin, tb);
    deg_kernel<<<dim3(NBF, c), 256, 0, stream>>>(cursor, bin, dinv);
    gather_agg_kernel<<<NBF, 256, 0, stream>>>(x, xh, dinv, cursor, bin,
                                               Mz, Bz, Mh, Bh, acc, tb, c);
  }

  out_kernel<<<(NN * OUT_C + 255) / 256, 256, 0, stream>>>(acc, W_out, b_out, out);
}

// Round 11
// 1426.462 us; speedup vs baseline: 1.1749x; 1.1749x over previous
//
#include <hip/hip_runtime.h>
#include <hip/hip_fp16.h>

#define NN 50000
#define TT 12
#define EE 800000
#define IN_C 32
#define HID 64
#define OUT_C 32
#define BSZ 64                        // nodes per bucket
#define NB ((NN + BSZ - 1) / BSZ)     // 782
#define CAP 1600                      // slots per (t,bucket); mean 1024
#define EPB 8192                      // edges per bin block
#define ABLK ((EE + EPB - 1) / EPB)   // 98
#define NPW 8                         // nodes per wave in gather
#define GBLK ((NN + 31) / 32)         // 1563 gather blocks (32 nodes/block)
#define XPAIRS ((size_t)TT * NN * 16) // half2 elements in x

// ---------------- precompute folded gate matrices ----------------
// Mz = Wz @ Lz_w[:64] (32x64), Bz = bz @ Lz_w[:64] + Lz_b (64); same for h.
__global__ __launch_bounds__(64) void prep_kernel(
    const float* __restrict__ Wz, const float* __restrict__ bz,
    const float* __restrict__ Lzw, const float* __restrict__ Lzb,
    const float* __restrict__ Wh, const float* __restrict__ bh,
    const float* __restrict__ Lhw, const float* __restrict__ Lhb,
    float* __restrict__ Mz, float* __restrict__ Bz,
    float* __restrict__ Mh, float* __restrict__ Bh) {
  const int j = threadIdx.x;
  const int i = blockIdx.x;
  const int h = blockIdx.y;
  const float* W  = h ? Wh  : Wz;
  const float* b  = h ? bh  : bz;
  const float* L  = h ? Lhw : Lzw;
  const float* Lb = h ? Lhb : Lzb;
  float* M = h ? Mh : Mz;
  float* B = h ? Bh : Bz;
  if (i < IN_C) {
    float v = 0.f;
    for (int k = 0; k < HID; ++k) v += W[i * HID + k] * L[k * HID + j];
    M[i * HID + j] = v;
  } else {
    float v = Lb[j];
    for (int k = 0; k < HID; ++k) v += b[k] * L[k * HID + j];
    B[j] = v;
  }
}

// x [T,N,32] fp32 -> fp16 pairs
__global__ __launch_bounds__(256) void xconv_kernel(const float* __restrict__ x,
                                                    __half2* __restrict__ xh) {
  size_t i = (size_t)blockIdx.x * 256 + threadIdx.x;
  if (i < XPAIRS) {
    float2 f = ((const float2*)x)[i];
    xh[i] = __floats2half2_rn(f.x, f.y);
  }
}

// Pass A: coarse-bucket multisplit (proven R8/R9).
// Entries {src16 | (dst&63)<<16 | w16<<32} bucket-grouped.
__global__ __launch_bounds__(256) void bin_kernel(const int* __restrict__ ei,
                                                  const float* __restrict__ ew,
                                                  int* __restrict__ cursorA,
                                                  unsigned long long* __restrict__ binA,
                                                  int tbase) {
  __shared__ int hist[NB];
  __shared__ int rnk[NB];
  int tl = blockIdx.y;
  const int* src = ei + (size_t)(tbase + tl) * 2 * EE;
  const int* dst = src + EE;
  const float* w = ew + (size_t)(tbase + tl) * EE;
  int* cursor = cursorA + (size_t)tl * NB;
  unsigned long long* bin = binA + (size_t)tl * NB * CAP;
  int t = threadIdx.x;
  for (int i = t; i < NB; i += 256) { hist[i] = 0; rnk[i] = 0; }
  __syncthreads();
  int e0 = blockIdx.x * EPB;
#pragma unroll
  for (int i = 0; i < EPB / 256; ++i) {
    int e = e0 + i * 256 + t;
    if (e < EE) atomicAdd(&hist[dst[e] >> 6], 1);
  }
  __syncthreads();
  for (int b = t; b < NB; b += 256)
    hist[b] = atomicAdd(&cursor[b], hist[b]);  // hist becomes this block's base
  __syncthreads();
#pragma unroll
  for (int i = 0; i < EPB / 256; ++i) {
    int e = e0 + i * 256 + t;
    if (e < EE) {
      int d = dst[e], s = src[e];
      int b = d >> 6;
      unsigned short hw = __half_as_ushort(__float2half_rn(w[e]));
      int pos = hist[b] + atomicAdd(&rnk[b], 1);
      if (pos < CAP)
        bin[(size_t)b * CAP + pos] =
            (unsigned long long)((unsigned)s | ((unsigned)(d & 63) << 16)) |
            ((unsigned long long)hw << 32);
    }
  }
}

// per (bucket,t): deg = 1 + sum w over bucket entries, dinv = rsqrt(deg)
__global__ __launch_bounds__(256) void deg_kernel(const int* __restrict__ cursorA,
                                                  const unsigned long long* __restrict__ binA,
                                                  float* __restrict__ dinvA) {
  __shared__ float wsum[BSZ];
  int tl = blockIdx.y, b = blockIdx.x;
  int t = threadIdx.x;
  if (t < BSZ) wsum[t] = 0.f;
  __syncthreads();
  int cnt = min(cursorA[(size_t)tl * NB + b], CAP);
  const unsigned long long* bin = binA + ((size_t)tl * NB + b) * CAP;
  for (int i = t; i < cnt; i += 256) {
    unsigned long long u = bin[i];
    int dl = (int)((u >> 16) & 63u);
    float wv = __half2float(__ushort_as_half((unsigned short)(u >> 32)));
    atomicAdd(&wsum[dl], wv);
  }
  __syncthreads();
  int n = b * BSZ + t;
  if (t < BSZ && n < NN) dinvA[(size_t)tl * NN + n] = rsqrtf(1.0f + wsum[t]);
}

// exclusive scan of clamped bucket counts -> bucket bases (per t)
__global__ __launch_bounds__(1024) void bscan_kernel(const int* __restrict__ cursorA,
                                                     int* __restrict__ bbaseA) {
  __shared__ int s[1024];
  int tl = blockIdx.x, t = threadIdx.x;
  int v = (t < NB) ? min(cursorA[(size_t)tl * NB + t], CAP) : 0;
  s[t] = v;
  __syncthreads();
  for (int o = 1; o < 1024; o <<= 1) {
    int u = (t >= o) ? s[t - o] : 0;
    __syncthreads();
    s[t] += u;
    __syncthreads();
  }
  if (t < NB) bbaseA[(size_t)tl * NB + t] = s[t] - v;  // exclusive
}

// per (bucket,t): counting-sort bucket entries by dst&63 into global CSR
// sbufG {src16 | fp16(w*dinv[src])<<16}; write noffG per node.
__global__ __launch_bounds__(256) void sort_kernel(
    const int* __restrict__ cursorA, const int* __restrict__ bbaseA,
    const unsigned long long* __restrict__ binA, const float* __restrict__ dinvA,
    unsigned* __restrict__ sbufG, int* __restrict__ noffG) {
  __shared__ int hist[BSZ + 1];
  __shared__ int plc[BSZ];
  int tl = blockIdx.y, b = blockIdx.x;
  int t = threadIdx.x;
  if (t < BSZ + 1) hist[t] = 0;
  __syncthreads();
  int cnt = min(cursorA[(size_t)tl * NB + b], CAP);
  int base = bbaseA[(size_t)tl * NB + b];
  const unsigned long long* bin = binA + ((size_t)tl * NB + b) * CAP;
  const float* dinv = dinvA + (size_t)tl * NN;
  unsigned* sbuf = sbufG + (size_t)tl * EE;
  int* noff = noffG + (size_t)tl * (NN + 1);
  for (int e = t; e < cnt; e += 256)
    atomicAdd(&hist[(int)((bin[e] >> 16) & 63u)], 1);
  __syncthreads();
  if (t == 0) {
    int run = 0;
#pragma unroll
    for (int i = 0; i < BSZ; ++i) {
      int c = hist[i];
      hist[i] = run;
      plc[i] = run;
      run += c;
    }
    hist[BSZ] = run;
    if (b == NB - 1) noff[NN] = base + run;
  }
  __syncthreads();
  {
    int n = b * BSZ + t;
    if (t < BSZ && n < NN) noff[n] = base + hist[t];
  }
  for (int e = t; e < cnt; e += 256) {
    unsigned long long u = bin[e];
    int s = (int)(u & 0xFFFFu);
    int dl = (int)((u >> 16) & 63u);
    float nm = __half2float(__ushort_as_half((unsigned short)(u >> 32))) * dinv[s];
    int pos = base + atomicAdd(&plc[dl], 1);
    sbuf[pos] = (unsigned)s | ((unsigned)__half_as_ushort(__float2half_rn(nm)) << 16);
  }
}

// Pass B: BARRIER-FREE gather+gate. 256 thr (4 waves) per 32 nodes; t-loop
// inside (near-full residency -> t-lockstep keeps xh_t L2-resident). Wave owns
// 8 nodes; lane = 8 edge-groups x 8 channel-quads; yt wave-private; register
// acc across all t. Only one __syncthreads (weight staging).
__global__ __launch_bounds__(256) void gather_agg_kernel(
    const float* __restrict__ x, const __half2* __restrict__ xh,
    const float* __restrict__ dinvA, const int* __restrict__ noffG,
    const unsigned* __restrict__ sbufG,
    const float* __restrict__ Mz, const float* __restrict__ Bz,
    const float* __restrict__ Mh, const float* __restrict__ Bh,
    float* __restrict__ acc, int tbase, int nt) {
  __shared__ float sMz[IN_C * HID], sMh[IN_C * HID], sBz[HID], sBh[HID];
  __shared__ float yt[4][IN_C];  // per-wave scratch
  int t = threadIdx.x;
  for (int i = t; i < IN_C * HID; i += 256) { sMz[i] = Mz[i]; sMh[i] = Mh[i]; }
  if (t < HID) { sBz[t] = Bz[t]; sBh[t] = Bh[t]; }
  __syncthreads();  // the only block barrier

  int w = t >> 6;      // wave 0..3
  int lane = t & 63;
  int g = lane >> 3;   // edge group 0..7
  int cl = lane & 7;   // channel quad 0..7
  int nb0 = blockIdx.x * 32 + w * NPW;  // this wave's first node
  float accr[NPW];
#pragma unroll
  for (int k = 0; k < NPW; ++k) accr[k] = 0.f;

  for (int tl = 0; tl < nt; ++tl) {
    const float* dinv = dinvA + (size_t)tl * NN;
    const int* noff = noffG + (size_t)tl * (NN + 1);
    const unsigned* sbuf = sbufG + (size_t)tl * EE;
    const __half2* xht = xh + (size_t)(tbase + tl) * NN * 16;
    const float* xt = x + (size_t)(tbase + tl) * NN * IN_C;
#pragma unroll
    for (int k = 0; k < NPW; ++k) {
      int n = nb0 + k;
      if (n >= NN) break;
      int e0 = noff[n], e1 = noff[n + 1];
      float4 v = {0.f, 0.f, 0.f, 0.f};
      for (int e = e0 + g; e < e1; e += 8) {
        unsigned u = sbuf[e];  // 8 lanes same addr: L1 broadcast
        float nm = __half2float(__ushort_as_half((unsigned short)(u >> 16)));
        uint2 xr = ((const uint2*)(xht + (size_t)(u & 0xFFFFu) * 16))[cl];
        float2 p0 = __half22float2(*(const __half2*)&xr.x);
        float2 p1 = __half22float2(*(const __half2*)&xr.y);
        v.x += nm * p0.x; v.y += nm * p0.y;
        v.z += nm * p1.x; v.w += nm * p1.y;
      }
#pragma unroll
      for (int m = 8; m <= 32; m <<= 1) {
        v.x += __shfl_xor(v.x, m); v.y += __shfl_xor(v.y, m);
        v.z += __shfl_xor(v.z, m); v.w += __shfl_xor(v.w, m);
      }
      float dv = dinv[n];
      if (g == 0) {  // 8 lanes x float4 = all 32 channels; fp32 self-loop
        float4 xs = ((const float4*)(xt + (size_t)n * IN_C))[cl];
        float4 o;
        o.x = dv * (v.x + dv * xs.x);
        o.y = dv * (v.y + dv * xs.y);
        o.z = dv * (v.z + dv * xs.z);
        o.w = dv * (v.w + dv * xs.w);
        *(float4*)&yt[w][cl * 4] = o;  // wave-private: in-order, no barrier
      }
      float za = sBz[lane], ha = sBh[lane];
#pragma unroll
      for (int c = 0; c < IN_C; ++c) {
        float yv = yt[w][c];  // wave-broadcast
        za += yv * sMz[c * HID + lane];
        ha += yv * sMh[c * HID + lane];
      }
      float z = 1.0f / (1.0f + expf(-za));
      accr[k] += (1.0f - z) * tanhf(ha);
    }
  }
#pragma unroll
  for (int k = 0; k < NPW; ++k) {
    int n = nb0 + k;
    if (n < NN) {
      size_t ai = (size_t)n * HID + lane;
      acc[ai] = (tbase == 0 ? 0.f : acc[ai]) + accr[k];
    }
  }
}

// out[n][o] = (acc[n]/T) . W_out[:,o] + b_out[o]
__global__ __launch_bounds__(256) void out_kernel(const float* __restrict__ acc,
                                                  const float* __restrict__ W_out,
                                                  const float* __restrict__ b_out,
                                                  float* __restrict__ out) {
  __shared__ float sW[HID * OUT_C], sB[OUT_C];
  for (int i = threadIdx.x; i < HID * OUT_C; i += 256) sW[i] = W_out[i];
  if (threadIdx.x < OUT_C) sB[threadIdx.x] = b_out[threadIdx.x];
  __syncthreads();
  unsigned tid = blockIdx.x * 256u + threadIdx.x;
  unsigned n = tid >> 5;
  int o = tid & 31;
  if (n >= NN) return;
  const float* ar = acc + (size_t)n * HID;
  float v = 0.f;
#pragma unroll
  for (int k = 0; k < HID; ++k) v += ar[k] * sW[k * OUT_C + o];
  out[(size_t)n * OUT_C + o] = v * (1.0f / (float)TT) + sB[o];
}

static inline char* alignp(char* p, size_t a) {
  return (char*)(((size_t)p + a - 1) & ~(a - 1));
}

extern "C" void kernel_launch(void* const* d_in, const int* in_sizes, int n_in,
                              void* d_out, int out_size, void* d_ws, size_t ws_size,
                              hipStream_t stream) {
  const float* x     = (const float*)d_in[0];  // [T,N,32]
  const int*   ei    = (const int*)d_in[1];    // [T,2,E]
  const float* ew    = (const float*)d_in[2];  // [T,E]
  const float* Wz    = (const float*)d_in[3];
  const float* bz    = (const float*)d_in[4];
  // d_in[5..6] (Wr,br) dead: H==0 so R unused
  const float* Wh    = (const float*)d_in[7];
  const float* bh    = (const float*)d_in[8];
  const float* Lz_w  = (const float*)d_in[9];
  const float* Lz_b  = (const float*)d_in[10];
  // d_in[11..12] (Lr) dead
  const float* Lh_w  = (const float*)d_in[13];
  const float* Lh_b  = (const float*)d_in[14];
  const float* W_out = (const float*)d_in[15];
  const float* b_out = (const float*)d_in[16];
  float* out = (float*)d_out;

  // per-t sizes (bytes)
  const size_t binB   = (size_t)NB * CAP * 8;     // 10.0 MB
  const size_t curB   = (size_t)NB * 4;
  const size_t bbB    = (size_t)NB * 4;
  const size_t dinvB  = (size_t)NN * 4;
  const size_t noffB  = (size_t)(NN + 1) * 4;
  const size_t sbufB  = (size_t)EE * 4;           // 3.2 MB
  const size_t perT   = binB + curB + bbB + dinvB + noffB + sbufB;  // ~13.6 MB
  const size_t xhB    = XPAIRS * 4;               // 38.4 MB
  const size_t fixedB = 4 * ((size_t)2 * IN_C * HID + 2 * HID)
                      + (size_t)NN * HID * 4 + xhB + 4096;  // ~51.3 MB

  int nt = 12;
  if (ws_size < fixedB + 12 * perT) {
    nt = (int)((ws_size - fixedB) / perT);
    if (nt < 1) nt = 1;
    if (nt > 12) nt = 12;
  }

  char* p = (char*)d_ws;
  unsigned long long* bin = (unsigned long long*)p;  // 8-aligned at base
  p += binB * nt;
  int* cursor = (int*)p;   p += curB * nt;
  int* bbase  = (int*)p;   p += bbB * nt;
  float* dinv = (float*)p; p += dinvB * nt;
  int* noffG  = (int*)p;   p += noffB * nt;
  unsigned* sbufG = (unsigned*)p; p += sbufB * nt;
  float* Mz = (float*)p;
  float* Mh = Mz + IN_C * HID;
  float* Bz = Mh + IN_C * HID;
  float* Bh = Bz + HID;
  float* acc = Bh + HID;  // [N,64]
  p = alignp((char*)(acc + (size_t)NN * HID), 256);
  __half2* xh = (__half2*)p;

  prep_kernel<<<dim3(IN_C + 1, 2), 64, 0, stream>>>(Wz, bz, Lz_w, Lz_b, Wh, bh,
                                                    Lh_w, Lh_b, Mz, Bz, Mh, Bh);
  xconv_kernel<<<(unsigned)((XPAIRS + 255) / 256), 256, 0, stream>>>(x, xh);

  for (int tb = 0; tb < TT; tb += nt) {
    int c = (TT - tb < nt) ? (TT - tb) : nt;
    hipMemsetAsync(cursor, 0, curB * c, stream);
    bin_kernel<<<dim3(ABLK, c), 256, 0, stream>>>(ei, ew, cursor, bin, tb);
    deg_kernel<<<dim3(NB, c), 256, 0, stream>>>(cursor, bin, dinv);
    bscan_kernel<<<c, 1024, 0, stream>>>(cursor, bbase);
    sort_kernel<<<dim3(NB, c), 256, 0, stream>>>(cursor, bbase, bin, dinv,
                                                 sbufG, noffG);
    gather_agg_kernel<<<GBLK, 256, 0, stream>>>(x, xh, dinv, noffG, sbufG,
                                                Mz, Bz, Mh, Bh, acc, tb, c);
  }

  out_kernel<<<(NN * OUT_C + 255) / 256, 256, 0, stream>>>(acc, W_out, b_out, out);
}

// Round 12
// 960.767 us; speedup vs baseline: 1.7444x; 1.4847x over previous
//
#include <hip/hip_runtime.h>
#include <hip/hip_fp16.h>

#define NN 50000
#define TT 12
#define EE 800000
#define IN_C 32
#define HID 64
#define OUT_C 32
#define BSZ 64                        // nodes per bucket
#define NB ((NN + BSZ - 1) / BSZ)     // 782
#define CAP 1600                      // slots per (t,bucket); mean 1024
#define EPB 8192                      // edges per bin block
#define ABLK ((EE + EPB - 1) / EPB)   // 98
#define XPAIRS ((size_t)TT * NN * 16) // half2 elements in x

// ---------------- precompute folded gate matrices ----------------
// Mz = Wz @ Lz_w[:64] (32x64), Bz = bz @ Lz_w[:64] + Lz_b (64); same for h.
__global__ __launch_bounds__(64) void prep_kernel(
    const float* __restrict__ Wz, const float* __restrict__ bz,
    const float* __restrict__ Lzw, const float* __restrict__ Lzb,
    const float* __restrict__ Wh, const float* __restrict__ bh,
    const float* __restrict__ Lhw, const float* __restrict__ Lhb,
    float* __restrict__ Mz, float* __restrict__ Bz,
    float* __restrict__ Mh, float* __restrict__ Bh) {
  const int j = threadIdx.x;
  const int i = blockIdx.x;
  const int h = blockIdx.y;
  const float* W  = h ? Wh  : Wz;
  const float* b  = h ? bh  : bz;
  const float* L  = h ? Lhw : Lzw;
  const float* Lb = h ? Lhb : Lzb;
  float* M = h ? Mh : Mz;
  float* B = h ? Bh : Bz;
  if (i < IN_C) {
    float v = 0.f;
    for (int k = 0; k < HID; ++k) v += W[i * HID + k] * L[k * HID + j];
    M[i * HID + j] = v;
  } else {
    float v = Lb[j];
    for (int k = 0; k < HID; ++k) v += b[k] * L[k * HID + j];
    B[j] = v;
  }
}

// x [T,N,32] fp32 -> fp16 pairs
__global__ __launch_bounds__(256) void xconv_kernel(const float* __restrict__ x,
                                                    __half2* __restrict__ xh) {
  size_t i = (size_t)blockIdx.x * 256 + threadIdx.x;
  if (i < XPAIRS) {
    float2 f = ((const float2*)x)[i];
    xh[i] = __floats2half2_rn(f.x, f.y);
  }
}

// Pass A: coarse-bucket multisplit (proven R8-R11).
// Entries {src16 | (dst&63)<<16 | w16<<32} bucket-grouped.
__global__ __launch_bounds__(256) void bin_kernel(const int* __restrict__ ei,
                                                  const float* __restrict__ ew,
                                                  int* __restrict__ cursorA,
                                                  unsigned long long* __restrict__ binA,
                                                  int tbase) {
  __shared__ int hist[NB];
  __shared__ int rnk[NB];
  int tl = blockIdx.y;
  const int* src = ei + (size_t)(tbase + tl) * 2 * EE;
  const int* dst = src + EE;
  const float* w = ew + (size_t)(tbase + tl) * EE;
  int* cursor = cursorA + (size_t)tl * NB;
  unsigned long long* bin = binA + (size_t)tl * NB * CAP;
  int t = threadIdx.x;
  for (int i = t; i < NB; i += 256) { hist[i] = 0; rnk[i] = 0; }
  __syncthreads();
  int e0 = blockIdx.x * EPB;
#pragma unroll
  for (int i = 0; i < EPB / 256; ++i) {
    int e = e0 + i * 256 + t;
    if (e < EE) atomicAdd(&hist[dst[e] >> 6], 1);
  }
  __syncthreads();
  for (int b = t; b < NB; b += 256)
    hist[b] = atomicAdd(&cursor[b], hist[b]);  // hist becomes this block's base
  __syncthreads();
#pragma unroll
  for (int i = 0; i < EPB / 256; ++i) {
    int e = e0 + i * 256 + t;
    if (e < EE) {
      int d = dst[e], s = src[e];
      int b = d >> 6;
      unsigned short hw = __half_as_ushort(__float2half_rn(w[e]));
      int pos = hist[b] + atomicAdd(&rnk[b], 1);
      if (pos < CAP)
        bin[(size_t)b * CAP + pos] =
            (unsigned long long)((unsigned)s | ((unsigned)(d & 63) << 16)) |
            ((unsigned long long)hw << 32);
    }
  }
}

// per (bucket,t): deg = 1 + sum w over bucket entries, dinv = rsqrt(deg)
__global__ __launch_bounds__(256) void deg_kernel(const int* __restrict__ cursorA,
                                                  const unsigned long long* __restrict__ binA,
                                                  float* __restrict__ dinvA) {
  __shared__ float wsum[BSZ];
  int tl = blockIdx.y, b = blockIdx.x;
  int t = threadIdx.x;
  if (t < BSZ) wsum[t] = 0.f;
  __syncthreads();
  int cnt = min(cursorA[(size_t)tl * NB + b], CAP);
  const unsigned long long* bin = binA + ((size_t)tl * NB + b) * CAP;
  for (int i = t; i < cnt; i += 256) {
    unsigned long long u = bin[i];
    int dl = (int)((u >> 16) & 63u);
    float wv = __half2float(__ushort_as_half((unsigned short)(u >> 32)));
    atomicAdd(&wsum[dl], wv);
  }
  __syncthreads();
  int n = b * BSZ + t;
  if (t < BSZ && n < NN) dinvA[(size_t)tl * NN + n] = rsqrtf(1.0f + wsum[t]);
}

// exclusive scan of clamped bucket counts -> bucket bases (per t)
__global__ __launch_bounds__(1024) void bscan_kernel(const int* __restrict__ cursorA,
                                                     int* __restrict__ bbaseA) {
  __shared__ int s[1024];
  int tl = blockIdx.x, t = threadIdx.x;
  int v = (t < NB) ? min(cursorA[(size_t)tl * NB + t], CAP) : 0;
  s[t] = v;
  __syncthreads();
  for (int o = 1; o < 1024; o <<= 1) {
    int u = (t >= o) ? s[t - o] : 0;
    __syncthreads();
    s[t] += u;
    __syncthreads();
  }
  if (t < NB) bbaseA[(size_t)tl * NB + t] = s[t] - v;  // exclusive
}

// per (bucket,t): counting-sort bucket entries by dst&63 into global CSR
// sbufG {src16 | fp16(w*dinv[src])<<16}; write noffG per node.
__global__ __launch_bounds__(256) void sort_kernel(
    const int* __restrict__ cursorA, const int* __restrict__ bbaseA,
    const unsigned long long* __restrict__ binA, const float* __restrict__ dinvA,
    unsigned* __restrict__ sbufG, int* __restrict__ noffG) {
  __shared__ int hist[BSZ + 1];
  __shared__ int plc[BSZ];
  int tl = blockIdx.y, b = blockIdx.x;
  int t = threadIdx.x;
  if (t < BSZ + 1) hist[t] = 0;
  __syncthreads();
  int cnt = min(cursorA[(size_t)tl * NB + b], CAP);
  int base = bbaseA[(size_t)tl * NB + b];
  const unsigned long long* bin = binA + ((size_t)tl * NB + b) * CAP;
  const float* dinv = dinvA + (size_t)tl * NN;
  unsigned* sbuf = sbufG + (size_t)tl * EE;
  int* noff = noffG + (size_t)tl * (NN + 1);
  for (int e = t; e < cnt; e += 256)
    atomicAdd(&hist[(int)((bin[e] >> 16) & 63u)], 1);
  __syncthreads();
  if (t == 0) {
    int run = 0;
#pragma unroll
    for (int i = 0; i < BSZ; ++i) {
      int c = hist[i];
      hist[i] = run;
      plc[i] = run;
      run += c;
    }
    hist[BSZ] = run;
    if (b == NB - 1) noff[NN] = base + run;
  }
  __syncthreads();
  {
    int n = b * BSZ + t;
    if (t < BSZ && n < NN) noff[n] = base + hist[t];
  }
  for (int e = t; e < cnt; e += 256) {
    unsigned long long u = bin[e];
    int s = (int)(u & 0xFFFFu);
    int dl = (int)((u >> 16) & 63u);
    float nm = __half2float(__ushort_as_half((unsigned short)(u >> 32))) * dinv[s];
    int pos = base + atomicAdd(&plc[dl], 1);
    sbuf[pos] = (unsigned)s | ((unsigned)__half_as_ushort(__float2half_rn(nm)) << 16);
  }
}

// Pass B: t-major grid — blockIdx.y = timestep (slow dim), 12500 node-blocks
// per t. Resident cohort shares ONE 3.2 MB xh_t slice (L2-resident) at max
// node-parallelism (50k waves/t). Wave = one node at one t: lane = 8 edge
// groups x 8 channel quads; gate per lane-column; one coalesced atomicAdd
// per (node,col). acc zeroed by host-side memset per launch.
__global__ __launch_bounds__(256) void gather_agg_kernel(
    const float* __restrict__ x, const __half2* __restrict__ xh,
    const float* __restrict__ dinvA, const int* __restrict__ noffG,
    const unsigned* __restrict__ sbufG,
    const float* __restrict__ Mz, const float* __restrict__ Bz,
    const float* __restrict__ Mh, const float* __restrict__ Bh,
    float* __restrict__ acc, int tbase) {
  __shared__ float sMz[IN_C * HID], sMh[IN_C * HID], sBz[HID], sBh[HID];
  __shared__ float yt[4][IN_C];  // per-wave scratch
  int t = threadIdx.x;
  for (int i = t; i < IN_C * HID; i += 256) { sMz[i] = Mz[i]; sMh[i] = Mh[i]; }
  if (t < HID) { sBz[t] = Bz[t]; sBh[t] = Bh[t]; }
  __syncthreads();  // the only block barrier

  int w = t >> 6;      // wave 0..3
  int lane = t & 63;
  int g = lane >> 3;   // edge group 0..7
  int cl = lane & 7;   // channel quad 0..7
  int n = blockIdx.x * 4 + w;  // NN % 4 == 0, no tail
  int tl = blockIdx.y;

  const float* dinv = dinvA + (size_t)tl * NN;
  const int* noff = noffG + (size_t)tl * (NN + 1);
  const unsigned* sbuf = sbufG + (size_t)tl * EE;
  const __half2* xht = xh + (size_t)(tbase + tl) * NN * 16;
  const float* xt = x + (size_t)(tbase + tl) * NN * IN_C;

  int e0 = noff[n], e1 = noff[n + 1];
  float4 v = {0.f, 0.f, 0.f, 0.f};
  for (int e = e0 + g; e < e1; e += 8) {
    unsigned u = sbuf[e];  // 8 lanes same addr: broadcast
    float nm = __half2float(__ushort_as_half((unsigned short)(u >> 16)));
    uint2 xr = ((const uint2*)(xht + (size_t)(u & 0xFFFFu) * 16))[cl];
    float2 p0 = __half22float2(*(const __half2*)&xr.x);
    float2 p1 = __half22float2(*(const __half2*)&xr.y);
    v.x += nm * p0.x; v.y += nm * p0.y;
    v.z += nm * p1.x; v.w += nm * p1.y;
  }
#pragma unroll
  for (int m = 8; m <= 32; m <<= 1) {
    v.x += __shfl_xor(v.x, m); v.y += __shfl_xor(v.y, m);
    v.z += __shfl_xor(v.z, m); v.w += __shfl_xor(v.w, m);
  }
  float dv = dinv[n];
  if (g == 0) {  // 8 lanes x float4 = all 32 channels; fp32 self-loop
    float4 xs = ((const float4*)(xt + (size_t)n * IN_C))[cl];
    float4 o;
    o.x = dv * (v.x + dv * xs.x);
    o.y = dv * (v.y + dv * xs.y);
    o.z = dv * (v.z + dv * xs.z);
    o.w = dv * (v.w + dv * xs.w);
    *(float4*)&yt[w][cl * 4] = o;  // wave-private: in-order, no barrier
  }
  float za = sBz[lane], ha = sBh[lane];
#pragma unroll
  for (int c = 0; c < IN_C; ++c) {
    float yv = yt[w][c];  // wave-broadcast
    za += yv * sMz[c * HID + lane];
    ha += yv * sMh[c * HID + lane];
  }
  float z = 1.0f / (1.0f + expf(-za));
  atomicAdd(&acc[(size_t)n * HID + lane], (1.0f - z) * tanhf(ha));
}

// out[n][o] = (acc[n]/T) . W_out[:,o] + b_out[o]
__global__ __launch_bounds__(256) void out_kernel(const float* __restrict__ acc,
                                                  const float* __restrict__ W_out,
                                                  const float* __restrict__ b_out,
                                                  float* __restrict__ out) {
  __shared__ float sW[HID * OUT_C], sB[OUT_C];
  for (int i = threadIdx.x; i < HID * OUT_C; i += 256) sW[i] = W_out[i];
  if (threadIdx.x < OUT_C) sB[threadIdx.x] = b_out[threadIdx.x];
  __syncthreads();
  unsigned tid = blockIdx.x * 256u + threadIdx.x;
  unsigned n = tid >> 5;
  int o = tid & 31;
  if (n >= NN) return;
  const float* ar = acc + (size_t)n * HID;
  float v = 0.f;
#pragma unroll
  for (int k = 0; k < HID; ++k) v += ar[k] * sW[k * OUT_C + o];
  out[(size_t)n * OUT_C + o] = v * (1.0f / (float)TT) + sB[o];
}

static inline char* alignp(char* p, size_t a) {
  return (char*)(((size_t)p + a - 1) & ~(a - 1));
}

extern "C" void kernel_launch(void* const* d_in, const int* in_sizes, int n_in,
                              void* d_out, int out_size, void* d_ws, size_t ws_size,
                              hipStream_t stream) {
  const float* x     = (const float*)d_in[0];  // [T,N,32]
  const int*   ei    = (const int*)d_in[1];    // [T,2,E]
  const float* ew    = (const float*)d_in[2];  // [T,E]
  const float* Wz    = (const float*)d_in[3];
  const float* bz    = (const float*)d_in[4];
  // d_in[5..6] (Wr,br) dead: H==0 so R unused
  const float* Wh    = (const float*)d_in[7];
  const float* bh    = (const float*)d_in[8];
  const float* Lz_w  = (const float*)d_in[9];
  const float* Lz_b  = (const float*)d_in[10];
  // d_in[11..12] (Lr) dead
  const float* Lh_w  = (const float*)d_in[13];
  const float* Lh_b  = (const float*)d_in[14];
  const float* W_out = (const float*)d_in[15];
  const float* b_out = (const float*)d_in[16];
  float* out = (float*)d_out;

  // per-t sizes (bytes)
  const size_t binB   = (size_t)NB * CAP * 8;     // 10.0 MB
  const size_t curB   = (size_t)NB * 4;
  const size_t bbB    = (size_t)NB * 4;
  const size_t dinvB  = (size_t)NN * 4;
  const size_t noffB  = (size_t)(NN + 1) * 4;
  const size_t sbufB  = (size_t)EE * 4;           // 3.2 MB
  const size_t perT   = binB + curB + bbB + dinvB + noffB + sbufB;  // ~13.6 MB
  const size_t xhB    = XPAIRS * 4;               // 38.4 MB
  const size_t fixedB = 4 * ((size_t)2 * IN_C * HID + 2 * HID)
                      + (size_t)NN * HID * 4 + xhB + 4096;  // ~51.3 MB

  int nt = 12;
  if (ws_size < fixedB + 12 * perT) {
    nt = (int)((ws_size - fixedB) / perT);
    if (nt < 1) nt = 1;
    if (nt > 12) nt = 12;
  }

  char* p = (char*)d_ws;
  unsigned long long* bin = (unsigned long long*)p;  // 8-aligned at base
  p += binB * nt;
  int* cursor = (int*)p;   p += curB * nt;
  int* bbase  = (int*)p;   p += bbB * nt;
  float* dinv = (float*)p; p += dinvB * nt;
  int* noffG  = (int*)p;   p += noffB * nt;
  unsigned* sbufG = (unsigned*)p; p += sbufB * nt;
  float* Mz = (float*)p;
  float* Mh = Mz + IN_C * HID;
  float* Bz = Mh + IN_C * HID;
  float* Bh = Bz + HID;
  float* acc = Bh + HID;  // [N,64]
  p = alignp((char*)(acc + (size_t)NN * HID), 256);
  __half2* xh = (__half2*)p;

  prep_kernel<<<dim3(IN_C + 1, 2), 64, 0, stream>>>(Wz, bz, Lz_w, Lz_b, Wh, bh,
                                                    Lh_w, Lh_b, Mz, Bz, Mh, Bh);
  xconv_kernel<<<(unsigned)((XPAIRS + 255) / 256), 256, 0, stream>>>(x, xh);
  hipMemsetAsync(acc, 0, (size_t)NN * HID * sizeof(float), stream);

  for (int tb = 0; tb < TT; tb += nt) {
    int c = (TT - tb < nt) ? (TT - tb) : nt;
    hipMemsetAsync(cursor, 0, curB * c, stream);
    bin_kernel<<<dim3(ABLK, c), 256, 0, stream>>>(ei, ew, cursor, bin, tb);
    deg_kernel<<<dim3(NB, c), 256, 0, stream>>>(cursor, bin, dinv);
    bscan_kernel<<<c, 1024, 0, stream>>>(cursor, bbase);
    sort_kernel<<<dim3(NB, c), 256, 0, stream>>>(cursor, bbase, bin, dinv,
                                                 sbufG, noffG);
    gather_agg_kernel<<<dim3(NN / 4, c), 256, 0, stream>>>(x, xh, dinv, noffG,
                                                           sbufG, Mz, Bz, Mh, Bh,
                                                           acc, tb);
  }

  out_kernel<<<(NN * OUT_C + 255) / 256, 256, 0, stream>>>(acc, W_out, b_out, out);
}

// Round 13
// 863.101 us; speedup vs baseline: 1.9418x; 1.1132x over previous
//
#include <hip/hip_runtime.h>
#include <hip/hip_fp16.h>

#define NN 50000
#define TT 12
#define EE 800000
#define IN_C 32
#define HID 64
#define OUT_C 32
#define BSZ 64                        // nodes per bucket
#define NB ((NN + BSZ - 1) / BSZ)     // 782
#define CAP 1600                      // slots per (t,bucket); mean 1024
#define EPB 8192                      // edges per bin block
#define ABLK ((EE + EPB - 1) / EPB)   // 98
#define XPAIRS ((size_t)TT * NN * 16) // half2 elements in x

// ---------------- precompute folded gate matrices ----------------
// Mz = Wz @ Lz_w[:64] (32x64), Bz = bz @ Lz_w[:64] + Lz_b (64); same for h.
__global__ __launch_bounds__(64) void prep_kernel(
    const float* __restrict__ Wz, const float* __restrict__ bz,
    const float* __restrict__ Lzw, const float* __restrict__ Lzb,
    const float* __restrict__ Wh, const float* __restrict__ bh,
    const float* __restrict__ Lhw, const float* __restrict__ Lhb,
    float* __restrict__ Mz, float* __restrict__ Bz,
    float* __restrict__ Mh, float* __restrict__ Bh) {
  const int j = threadIdx.x;
  const int i = blockIdx.x;
  const int h = blockIdx.y;
  const float* W  = h ? Wh  : Wz;
  const float* b  = h ? bh  : bz;
  const float* L  = h ? Lhw : Lzw;
  const float* Lb = h ? Lhb : Lzb;
  float* M = h ? Mh : Mz;
  float* B = h ? Bh : Bz;
  if (i < IN_C) {
    float v = 0.f;
    for (int k = 0; k < HID; ++k) v += W[i * HID + k] * L[k * HID + j];
    M[i * HID + j] = v;
  } else {
    float v = Lb[j];
    for (int k = 0; k < HID; ++k) v += b[k] * L[k * HID + j];
    B[j] = v;
  }
}

// x [T,N,32] fp32 -> fp16 pairs
__global__ __launch_bounds__(256) void xconv_kernel(const float* __restrict__ x,
                                                    __half2* __restrict__ xh) {
  size_t i = (size_t)blockIdx.x * 256 + threadIdx.x;
  if (i < XPAIRS) {
    float2 f = ((const float2*)x)[i];
    xh[i] = __floats2half2_rn(f.x, f.y);
  }
}

// Pass A: coarse-bucket multisplit (proven R8-R12).
// Entries {src16 | (dst&63)<<16 | w16<<32} bucket-grouped.
__global__ __launch_bounds__(256) void bin_kernel(const int* __restrict__ ei,
                                                  const float* __restrict__ ew,
                                                  int* __restrict__ cursorA,
                                                  unsigned long long* __restrict__ binA,
                                                  int tbase) {
  __shared__ int hist[NB];
  __shared__ int rnk[NB];
  int tl = blockIdx.y;
  const int* src = ei + (size_t)(tbase + tl) * 2 * EE;
  const int* dst = src + EE;
  const float* w = ew + (size_t)(tbase + tl) * EE;
  int* cursor = cursorA + (size_t)tl * NB;
  unsigned long long* bin = binA + (size_t)tl * NB * CAP;
  int t = threadIdx.x;
  for (int i = t; i < NB; i += 256) { hist[i] = 0; rnk[i] = 0; }
  __syncthreads();
  int e0 = blockIdx.x * EPB;
#pragma unroll
  for (int i = 0; i < EPB / 256; ++i) {
    int e = e0 + i * 256 + t;
    if (e < EE) atomicAdd(&hist[dst[e] >> 6], 1);
  }
  __syncthreads();
  for (int b = t; b < NB; b += 256)
    hist[b] = atomicAdd(&cursor[b], hist[b]);  // hist becomes this block's base
  __syncthreads();
#pragma unroll
  for (int i = 0; i < EPB / 256; ++i) {
    int e = e0 + i * 256 + t;
    if (e < EE) {
      int d = dst[e], s = src[e];
      int b = d >> 6;
      unsigned short hw = __half_as_ushort(__float2half_rn(w[e]));
      int pos = hist[b] + atomicAdd(&rnk[b], 1);
      if (pos < CAP)
        bin[(size_t)b * CAP + pos] =
            (unsigned long long)((unsigned)s | ((unsigned)(d & 63) << 16)) |
            ((unsigned long long)hw << 32);
    }
  }
}

// per (bucket,t): deg = 1 + sum w over bucket entries, dinv = rsqrt(deg)
__global__ __launch_bounds__(256) void deg_kernel(const int* __restrict__ cursorA,
                                                  const unsigned long long* __restrict__ binA,
                                                  float* __restrict__ dinvA) {
  __shared__ float wsum[BSZ];
  int tl = blockIdx.y, b = blockIdx.x;
  int t = threadIdx.x;
  if (t < BSZ) wsum[t] = 0.f;
  __syncthreads();
  int cnt = min(cursorA[(size_t)tl * NB + b], CAP);
  const unsigned long long* bin = binA + ((size_t)tl * NB + b) * CAP;
  for (int i = t; i < cnt; i += 256) {
    unsigned long long u = bin[i];
    int dl = (int)((u >> 16) & 63u);
    float wv = __half2float(__ushort_as_half((unsigned short)(u >> 32)));
    atomicAdd(&wsum[dl], wv);
  }
  __syncthreads();
  int n = b * BSZ + t;
  if (t < BSZ && n < NN) dinvA[(size_t)tl * NN + n] = rsqrtf(1.0f + wsum[t]);
}

// exclusive scan of clamped bucket counts -> bucket bases (per t)
__global__ __launch_bounds__(1024) void bscan_kernel(const int* __restrict__ cursorA,
                                                     int* __restrict__ bbaseA) {
  __shared__ int s[1024];
  int tl = blockIdx.x, t = threadIdx.x;
  int v = (t < NB) ? min(cursorA[(size_t)tl * NB + t], CAP) : 0;
  s[t] = v;
  __syncthreads();
  for (int o = 1; o < 1024; o <<= 1) {
    int u = (t >= o) ? s[t - o] : 0;
    __syncthreads();
    s[t] += u;
    __syncthreads();
  }
  if (t < NB) bbaseA[(size_t)tl * NB + t] = s[t] - v;  // exclusive
}

// per (bucket,t): counting-sort bucket entries by dst&63 into global CSR
// sbufG {src16 | fp16(w*dinv[src])<<16}; write noffG per node.
__global__ __launch_bounds__(256) void sort_kernel(
    const int* __restrict__ cursorA, const int* __restrict__ bbaseA,
    const unsigned long long* __restrict__ binA, const float* __restrict__ dinvA,
    unsigned* __restrict__ sbufG, int* __restrict__ noffG) {
  __shared__ int hist[BSZ + 1];
  __shared__ int plc[BSZ];
  int tl = blockIdx.y, b = blockIdx.x;
  int t = threadIdx.x;
  if (t < BSZ + 1) hist[t] = 0;
  __syncthreads();
  int cnt = min(cursorA[(size_t)tl * NB + b], CAP);
  int base = bbaseA[(size_t)tl * NB + b];
  const unsigned long long* bin = binA + ((size_t)tl * NB + b) * CAP;
  const float* dinv = dinvA + (size_t)tl * NN;
  unsigned* sbuf = sbufG + (size_t)tl * EE;
  int* noff = noffG + (size_t)tl * (NN + 1);
  for (int e = t; e < cnt; e += 256)
    atomicAdd(&hist[(int)((bin[e] >> 16) & 63u)], 1);
  __syncthreads();
  if (t == 0) {
    int run = 0;
#pragma unroll
    for (int i = 0; i < BSZ; ++i) {
      int c = hist[i];
      hist[i] = run;
      plc[i] = run;
      run += c;
    }
    hist[BSZ] = run;
    if (b == NB - 1) noff[NN] = base + run;
  }
  __syncthreads();
  {
    int n = b * BSZ + t;
    if (t < BSZ && n < NN) noff[n] = base + hist[t];
  }
  for (int e = t; e < cnt; e += 256) {
    unsigned long long u = bin[e];
    int s = (int)(u & 0xFFFFu);
    int dl = (int)((u >> 16) & 63u);
    float nm = __half2float(__ushort_as_half((unsigned short)(u >> 32))) * dinv[s];
    int pos = base + atomicAdd(&plc[dl], 1);
    sbuf[pos] = (unsigned)s | ((unsigned)__half_as_ushort(__float2half_rn(nm)) << 16);
  }
}

// Pass B1: pure gather, NO LDS / NO barriers. t-major grid (blockIdx.y = t)
// keeps xh_t L2-resident (proven R12). Wave = 2 nodes (lane bit 5), each with
// 4 edge-groups x 8 channel-quads -> two independent load chains per wave.
// Writes y[t][n][32] fp16.
__global__ __launch_bounds__(256) void gather_y_kernel(
    const float* __restrict__ x, const __half2* __restrict__ xh,
    const float* __restrict__ dinvA, const int* __restrict__ noffG,
    const unsigned* __restrict__ sbufG, __half2* __restrict__ yG, int tbase) {
  int t = threadIdx.x;
  int w = t >> 6;        // wave 0..3
  int lane = t & 63;
  int h2 = lane >> 5;    // node half 0/1
  int sl = lane & 31;
  int g = sl >> 3;       // edge group 0..3
  int cl = sl & 7;       // channel quad 0..7
  int tl = blockIdx.y;
  int n = blockIdx.x * 8 + w * 2 + h2;  // NN % 8 == 0, no tail

  const float* dinv = dinvA + (size_t)tl * NN;
  const int* noff = noffG + (size_t)tl * (NN + 1);
  const unsigned* sbuf = sbufG + (size_t)tl * EE;
  const __half2* xht = xh + (size_t)(tbase + tl) * NN * 16;
  const float* xt = x + (size_t)(tbase + tl) * NN * IN_C;

  int e0 = noff[n], e1 = noff[n + 1];
  float4 v = {0.f, 0.f, 0.f, 0.f};
  for (int e = e0 + g; e < e1; e += 4) {
    unsigned u = sbuf[e];  // 8 lanes same addr: broadcast
    float nm = __half2float(__ushort_as_half((unsigned short)(u >> 16)));
    uint2 xr = ((const uint2*)(xht + (size_t)(u & 0xFFFFu) * 16))[cl];
    float2 p0 = __half22float2(*(const __half2*)&xr.x);
    float2 p1 = __half22float2(*(const __half2*)&xr.y);
    v.x += nm * p0.x; v.y += nm * p0.y;
    v.z += nm * p1.x; v.w += nm * p1.y;
  }
  // reduce over the 4 edge groups (lane bits 3,4 — stays within node half)
  v.x += __shfl_xor(v.x, 8);  v.y += __shfl_xor(v.y, 8);
  v.z += __shfl_xor(v.z, 8);  v.w += __shfl_xor(v.w, 8);
  v.x += __shfl_xor(v.x, 16); v.y += __shfl_xor(v.y, 16);
  v.z += __shfl_xor(v.z, 16); v.w += __shfl_xor(v.w, 16);
  if (g == 0) {  // 8 lanes per node x float4 = all 32 channels
    float dv = dinv[n];
    float4 xs = ((const float4*)(xt + (size_t)n * IN_C))[cl];  // fp32 self-loop
    __half2 o0 = __floats2half2_rn(dv * (v.x + dv * xs.x), dv * (v.y + dv * xs.y));
    __half2 o1 = __floats2half2_rn(dv * (v.z + dv * xs.z), dv * (v.w + dv * xs.w));
    __half2* yp = yG + ((size_t)tl * NN + n) * 16 + cl * 2;
    yp[0] = o0;
    yp[1] = o1;
  }
}

// Pass B2: gate + accumulate. 782 blocks; weights staged ONCE per block;
// t-loop inside with register accr[16]; per t stage a 64-node y tile (4 KB,
// coalesced) -> fp32 LDS, then broadcast-FMA gate. No atomics, no acc memset.
__global__ __launch_bounds__(256) void gate_acc_kernel(
    const __half2* __restrict__ yG,
    const float* __restrict__ Mz, const float* __restrict__ Bz,
    const float* __restrict__ Mh, const float* __restrict__ Bh,
    float* __restrict__ acc, int tbase, int nt) {
  __shared__ float sMz[IN_C * HID], sMh[IN_C * HID], sBz[HID], sBh[HID];
  __shared__ float ytf[64][IN_C];
  int t = threadIdx.x;
  for (int i = t; i < IN_C * HID; i += 256) { sMz[i] = Mz[i]; sMh[i] = Mh[i]; }
  if (t < HID) { sBz[t] = Bz[t]; sBh[t] = Bh[t]; }
  int nb = blockIdx.x * 64;
  int j = t & 63;
  int nl4 = t >> 6;
  float accr[16];
#pragma unroll
  for (int k = 0; k < 16; ++k) accr[k] = 0.f;

  for (int tl = 0; tl < nt; ++tl) {
    __syncthreads();  // prev compute reads done before ytf overwrite
    int nn = nb + (t >> 2);
    int c0 = (t & 3) * 8;
    if (nn < NN) {
      // 8 fp16 channels per thread; full tile = 64 nodes x 32 ch
      uint4 q = *(const uint4*)(yG + ((size_t)tl * NN + nn) * 16 + c0 / 2);
      const __half2* hp = (const __half2*)&q;
#pragma unroll
      for (int i = 0; i < 4; ++i) {
        float2 f = __half22float2(hp[i]);
        ytf[t >> 2][c0 + 2 * i]     = f.x;
        ytf[t >> 2][c0 + 2 * i + 1] = f.y;
      }
    }
    __syncthreads();
#pragma unroll
    for (int k = 0; k < 16; ++k) {
      int nl = (k << 2) | nl4;
      if (nb + nl < NN) {
        float za = sBz[j], ha = sBh[j];
#pragma unroll
        for (int c = 0; c < IN_C; ++c) {
          float yv = ytf[nl][c];  // wave-broadcast
          za += yv * sMz[c * HID + j];
          ha += yv * sMh[c * HID + j];
        }
        float z = 1.0f / (1.0f + expf(-za));
        accr[k] += (1.0f - z) * tanhf(ha);
      }
    }
  }
#pragma unroll
  for (int k = 0; k < 16; ++k) {
    int n = nb + ((k << 2) | nl4);
    if (n < NN) {
      size_t ai = (size_t)n * HID + j;
      acc[ai] = (tbase == 0 ? 0.f : acc[ai]) + accr[k];
    }
  }
}

// out[n][o] = (acc[n]/T) . W_out[:,o] + b_out[o]
__global__ __launch_bounds__(256) void out_kernel(const float* __restrict__ acc,
                                                  const float* __restrict__ W_out,
                                                  const float* __restrict__ b_out,
                                                  float* __restrict__ out) {
  __shared__ float sW[HID * OUT_C], sB[OUT_C];
  for (int i = threadIdx.x; i < HID * OUT_C; i += 256) sW[i] = W_out[i];
  if (threadIdx.x < OUT_C) sB[threadIdx.x] = b_out[threadIdx.x];
  __syncthreads();
  unsigned tid = blockIdx.x * 256u + threadIdx.x;
  unsigned n = tid >> 5;
  int o = tid & 31;
  if (n >= NN) return;
  const float* ar = acc + (size_t)n * HID;
  float v = 0.f;
#pragma unroll
  for (int k = 0; k < HID; ++k) v += ar[k] * sW[k * OUT_C + o];
  out[(size_t)n * OUT_C + o] = v * (1.0f / (float)TT) + sB[o];
}

static inline char* alignp(char* p, size_t a) {
  return (char*)(((size_t)p + a - 1) & ~(a - 1));
}

extern "C" void kernel_launch(void* const* d_in, const int* in_sizes, int n_in,
                              void* d_out, int out_size, void* d_ws, size_t ws_size,
                              hipStream_t stream) {
  const float* x     = (const float*)d_in[0];  // [T,N,32]
  const int*   ei    = (const int*)d_in[1];    // [T,2,E]
  const float* ew    = (const float*)d_in[2];  // [T,E]
  const float* Wz    = (const float*)d_in[3];
  const float* bz    = (const float*)d_in[4];
  // d_in[5..6] (Wr,br) dead: H==0 so R unused
  const float* Wh    = (const float*)d_in[7];
  const float* bh    = (const float*)d_in[8];
  const float* Lz_w  = (const float*)d_in[9];
  const float* Lz_b  = (const float*)d_in[10];
  // d_in[11..12] (Lr) dead
  const float* Lh_w  = (const float*)d_in[13];
  const float* Lh_b  = (const float*)d_in[14];
  const float* W_out = (const float*)d_in[15];
  const float* b_out = (const float*)d_in[16];
  float* out = (float*)d_out;

  // per-t sizes (bytes)
  const size_t binB   = (size_t)NB * CAP * 8;     // 10.0 MB (y aliases this: 3.2 MB/t)
  const size_t curB   = (size_t)NB * 4;
  const size_t bbB    = (size_t)NB * 4;
  const size_t dinvB  = (size_t)NN * 4;
  const size_t noffB  = (size_t)(NN + 1) * 4;
  const size_t sbufB  = (size_t)EE * 4;           // 3.2 MB
  const size_t perT   = binB + curB + bbB + dinvB + noffB + sbufB;  // ~13.6 MB
  const size_t xhB    = XPAIRS * 4;               // 38.4 MB
  const size_t fixedB = 4 * ((size_t)2 * IN_C * HID + 2 * HID)
                      + (size_t)NN * HID * 4 + xhB + 4096;  // ~51.3 MB

  int nt = 12;
  if (ws_size < fixedB + 12 * perT) {
    nt = (int)((ws_size - fixedB) / perT);
    if (nt < 1) nt = 1;
    if (nt > 12) nt = 12;
  }

  char* p = (char*)d_ws;
  unsigned long long* bin = (unsigned long long*)p;  // 8-aligned at base
  p += binB * nt;
  int* cursor = (int*)p;   p += curB * nt;
  int* bbase  = (int*)p;   p += bbB * nt;
  float* dinv = (float*)p; p += dinvB * nt;
  int* noffG  = (int*)p;   p += noffB * nt;
  unsigned* sbufG = (unsigned*)p; p += sbufB * nt;
  float* Mz = (float*)p;
  float* Mh = Mz + IN_C * HID;
  float* Bz = Mh + IN_C * HID;
  float* Bh = Bz + HID;
  float* acc = Bh + HID;  // [N,64]
  p = alignp((char*)(acc + (size_t)NN * HID), 256);
  __half2* xh = (__half2*)p;
  // y [nt,N,32] fp16 aliases the bin region: bin is dead after sort_kernel,
  // and stream order guarantees sort (reads bin) < gather_y (writes y) <
  // gate_acc (reads y) < next chunk's bin_kernel (rewrites bin).
  __half2* yG = (__half2*)bin;

  prep_kernel<<<dim3(IN_C + 1, 2), 64, 0, stream>>>(Wz, bz, Lz_w, Lz_b, Wh, bh,
                                                    Lh_w, Lh_b, Mz, Bz, Mh, Bh);
  xconv_kernel<<<(unsigned)((XPAIRS + 255) / 256), 256, 0, stream>>>(x, xh);

  for (int tb = 0; tb < TT; tb += nt) {
    int c = (TT - tb < nt) ? (TT - tb) : nt;
    hipMemsetAsync(cursor, 0, curB * c, stream);
    bin_kernel<<<dim3(ABLK, c), 256, 0, stream>>>(ei, ew, cursor, bin, tb);
    deg_kernel<<<dim3(NB, c), 256, 0, stream>>>(cursor, bin, dinv);
    bscan_kernel<<<c, 1024, 0, stream>>>(cursor, bbase);
    sort_kernel<<<dim3(NB, c), 256, 0, stream>>>(cursor, bbase, bin, dinv,
                                                 sbufG, noffG);
    gather_y_kernel<<<dim3(NN / 8, c), 256, 0, stream>>>(x, xh, dinv, noffG,
                                                         sbufG, yG, tb);
    gate_acc_kernel<<<NB, 256, 0, stream>>>(yG, Mz, Bz, Mh, Bh, acc, tb, c);
  }

  out_kernel<<<(NN * OUT_C + 255) / 256, 256, 0, stream>>>(acc, W_out, b_out, out);
}